// Round 16
// baseline (174.260 us; speedup 1.0000x reference)
//
#include <hip/hip_runtime.h>
#include <hip/hip_bf16.h>
#include <hip/hip_fp16.h>

// GCN regressor: 3x GCNConv(64->64, normalize=False) + mean-pool + MLP(64->32->16->1)
// Round 16 (on best=165.9us):
//  - agg reverted to x4 unroll (x8 was neutral->negative: latency floor reached).
//  - pool fused into agg layer 3 (agg_pool_kernel): relu'd outputs staged in LDS,
//    run-length reduced per channel, few atomics/block. Deletes hA store (6.4MB),
//    pool re-read (6.4MB), and the pool dispatch.
//  - scanB2 keeps sums/cnts zero-init fold.

#define HID 64
#define KNBLK 256

// ---- pass A: per-block, per-bucket histogram. bucket = dst >> 8 ----
__global__ __launch_bounds__(256) void histA_kernel(const int* __restrict__ ei,
                                                    int* __restrict__ counts,
                                                    int E, int K, int chunk) {
    __shared__ int hist[256];
    int t = threadIdx.x, b = blockIdx.x;
    hist[t] = 0;
    __syncthreads();
    int s = b * chunk, e1 = min(E, s + chunk);
    for (int i = s + t; i < e1; i += 256)
        atomicAdd(&hist[ei[E + i] >> 8], 1);
    __syncthreads();
    if (t < K) counts[b * K + t] = hist[t];
}

// ---- scan B1 ----
__global__ __launch_bounds__(256) void scanB1_kernel(int* __restrict__ counts,
                                                     int* __restrict__ btot, int K) {
    __shared__ int sh[256];
    int k = blockIdx.x, t = threadIdx.x;
    int v = counts[t * K + k];
    sh[t] = v;
    __syncthreads();
    #pragma unroll
    for (int d = 1; d < 256; d <<= 1) {
        int add = (t >= d) ? sh[t - d] : 0;
        __syncthreads();
        sh[t] += add;
        __syncthreads();
    }
    counts[t * K + k] = sh[t] - v;
    if (t == 255) btot[k] = sh[255];
}

// ---- scan B2 (+ zero-init of pool accumulators) ----
__global__ __launch_bounds__(256) void scanB2_kernel(const int* __restrict__ btot,
                                                     int* __restrict__ bb0, int K,
                                                     float* __restrict__ sums,
                                                     float* __restrict__ cnts, int G) {
    __shared__ int sh[256];
    int t = threadIdx.x;
    int v = (t < K) ? btot[t] : 0;
    sh[t] = v;
    __syncthreads();
    #pragma unroll
    for (int d = 1; d < 256; d <<= 1) {
        int add = (t >= d) ? sh[t - d] : 0;
        __syncthreads();
        sh[t] += add;
        __syncthreads();
    }
    if (t < K) bb0[t] = sh[t] - v;
    if (t == 255) bb0[K] = sh[255];
    for (int i = t; i < G * 64; i += 256) sums[i] = 0.f;
    if (t < G) cnts[t] = 0.f;
}

// ---- pass B: scatter edges to bucket-partitioned ebuf (packed int2 records) ----
__global__ __launch_bounds__(256) void passB_kernel(const int* __restrict__ ei,
                                                    const float* __restrict__ ew,
                                                    const int* __restrict__ counts,
                                                    const int* __restrict__ bb0,
                                                    int2* __restrict__ ebuf,
                                                    int E, int K, int chunk) {
    __shared__ int lcur[256];
    int t = threadIdx.x, b = blockIdx.x;
    lcur[t] = 0;
    __syncthreads();
    int s = b * chunk, e1 = min(E, s + chunk);
    for (int i = s + t; i < e1; i += 256) {
        int src = ei[i];
        int dst = ei[E + i];
        float w = ew[i];
        int k = dst >> 8;
        int idx = atomicAdd(&lcur[k], 1);
        int slot = bb0[k] + counts[b * K + k] + idx;
        ebuf[slot] = make_int2(src | ((dst & 255) << 16), __float_as_int(w));
    }
}

// ---- pass C: per-bucket counting sort -> final CSR (int2{src,wbits}) + offs ----
__global__ __launch_bounds__(256) void passC_kernel(const int2* __restrict__ ebuf,
                                                    const int* __restrict__ bb0,
                                                    int2* __restrict__ csr,
                                                    int* __restrict__ offs,
                                                    int N, int E, int K) {
    __shared__ int ldeg[256];
    __shared__ int sh[256];
    __shared__ int lofs[256];
    int b = blockIdx.x, t = threadIdx.x;
    int gb0 = bb0[b], gb1 = bb0[b + 1];
    int cnt = gb1 - gb0;
    int base = b << 8;
    ldeg[t] = 0;
    __syncthreads();
    for (int i = t; i < cnt; i += 256)
        atomicAdd(&ldeg[(ebuf[gb0 + i].x >> 16) & 255], 1);
    __syncthreads();
    int v = ldeg[t];
    sh[t] = v;
    __syncthreads();
    #pragma unroll
    for (int d = 1; d < 256; d <<= 1) {
        int add = (t >= d) ? sh[t - d] : 0;
        __syncthreads();
        sh[t] += add;
        __syncthreads();
    }
    lofs[t] = sh[t] - v;
    int nInB = min(256, N - base);
    if (t < nInB) offs[base + t] = gb0 + lofs[t];
    if (b == K - 1 && t == 0) offs[N] = E;
    __syncthreads();
    for (int i = t; i < cnt; i += 256) {
        int2 r = ebuf[gb0 + i];
        int d = (r.x >> 16) & 255;
        int pos = atomicAdd(&lofs[d], 1);
        csr[gb0 + pos] = make_int2(r.x & 0xFFFF, r.y);
    }
}

// ---- fp32 -> fp16 conversion (x table), 4 elems/thread ----
__global__ __launch_bounds__(256) void conv_kernel(const float* __restrict__ in,
                                                   __half* __restrict__ out, int n4) {
    int i = blockIdx.x * 256 + threadIdx.x;
    if (i < n4) {
        const float4 v = *reinterpret_cast<const float4*>(in + (size_t)i * 4);
        __half2 a = __float22half2_rn(make_float2(v.x, v.y));
        __half2 b = __float22half2_rn(make_float2(v.z, v.w));
        uint2 u;
        u.x = __builtin_bit_cast(unsigned int, a);
        u.y = __builtin_bit_cast(unsigned int, b);
        *reinterpret_cast<uint2*>(out + (size_t)i * 4) = u;
    }
}

#define GLOAD(R, U)                                                              \
    const uint4 U = *reinterpret_cast<const uint4*>(prev + (size_t)(R).x * 64 + l * 8);
#define GACC(U, WW)                                                              \
    {                                                                            \
        const float2 f0 = __half22float2(__builtin_bit_cast(__half2, (U).x));    \
        const float2 f1 = __half22float2(__builtin_bit_cast(__half2, (U).y));    \
        const float2 f2 = __half22float2(__builtin_bit_cast(__half2, (U).z));    \
        const float2 f3 = __half22float2(__builtin_bit_cast(__half2, (U).w));    \
        acc[0] = fmaf((WW), f0.x, acc[0]); acc[1] = fmaf((WW), f0.y, acc[1]);    \
        acc[2] = fmaf((WW), f1.x, acc[2]); acc[3] = fmaf((WW), f1.y, acc[3]);    \
        acc[4] = fmaf((WW), f2.x, acc[4]); acc[5] = fmaf((WW), f2.y, acc[5]);    \
        acc[6] = fmaf((WW), f3.x, acc[6]); acc[7] = fmaf((WW), f3.y, acc[7]);    \
    }

// Fused layer (layers 1-2): out[n][:] = relu( agg(prev)[n] @ W + b ), fp16 store.
// 8 lanes/node; lane l owns channels 8l..8l+7; x4 unroll (round-13 structure).
__global__ __launch_bounds__(256) void agg_fused_kernel(const __half* __restrict__ prev,
                                                        const int2* __restrict__ csr,
                                                        const int* __restrict__ offs,
                                                        const float* __restrict__ W,
                                                        const float* __restrict__ bias,
                                                        __half* __restrict__ out, int N) {
    __shared__ float Wl[64 * 64];
    __shared__ float bl[64];
    for (int i = threadIdx.x; i < 64 * 64; i += 256) Wl[i] = W[i];
    if (threadIdx.x < 64) bl[threadIdx.x] = bias[threadIdx.x];
    __syncthreads();

    int g = (blockIdx.x * 256 + threadIdx.x) >> 3;   // node (8 lanes each)
    int l = threadIdx.x & 7;
    if (g >= N) return;

    int e0 = offs[g], e1 = offs[g + 1];
    float acc[8] = {0.f, 0.f, 0.f, 0.f, 0.f, 0.f, 0.f, 0.f};
    int e = e0;
    for (; e + 4 <= e1; e += 4) {
        int2 r0 = csr[e + 0];
        int2 r1 = csr[e + 1];
        int2 r2 = csr[e + 2];
        int2 r3 = csr[e + 3];
        GLOAD(r0, ua);
        GLOAD(r1, ub);
        GLOAD(r2, uc);
        GLOAD(r3, ud);
        GACC(ua, __int_as_float(r0.y));
        GACC(ub, __int_as_float(r1.y));
        GACC(uc, __int_as_float(r2.y));
        GACC(ud, __int_as_float(r3.y));
    }
    for (; e < e1; ++e) {
        int2 r = csr[e];
        GLOAD(r, ue);
        GACC(ue, __int_as_float(r.y));
    }

    float o[8];
    #pragma unroll
    for (int j = 0; j < 8; ++j) o[j] = bl[l * 8 + j];
    #pragma unroll
    for (int k2 = 0; k2 < 8; ++k2) {
        float c[8];
        #pragma unroll
        for (int j = 0; j < 8; ++j) c[j] = __shfl(acc[j], k2, 8);
        #pragma unroll
        for (int j = 0; j < 8; ++j) {
            const float4 wa = *reinterpret_cast<const float4*>(Wl + (8 * k2 + j) * 64 + l * 8);
            const float4 wb = *reinterpret_cast<const float4*>(Wl + (8 * k2 + j) * 64 + l * 8 + 4);
            o[0] = fmaf(c[j], wa.x, o[0]); o[1] = fmaf(c[j], wa.y, o[1]);
            o[2] = fmaf(c[j], wa.z, o[2]); o[3] = fmaf(c[j], wa.w, o[3]);
            o[4] = fmaf(c[j], wb.x, o[4]); o[5] = fmaf(c[j], wb.y, o[5]);
            o[6] = fmaf(c[j], wb.z, o[6]); o[7] = fmaf(c[j], wb.w, o[7]);
        }
    }
    uint4 u;
    u.x = __builtin_bit_cast(unsigned int,
          __float22half2_rn(make_float2(fmaxf(o[0], 0.f), fmaxf(o[1], 0.f))));
    u.y = __builtin_bit_cast(unsigned int,
          __float22half2_rn(make_float2(fmaxf(o[2], 0.f), fmaxf(o[3], 0.f))));
    u.z = __builtin_bit_cast(unsigned int,
          __float22half2_rn(make_float2(fmaxf(o[4], 0.f), fmaxf(o[5], 0.f))));
    u.w = __builtin_bit_cast(unsigned int,
          __float22half2_rn(make_float2(fmaxf(o[6], 0.f), fmaxf(o[7], 0.f))));
    *reinterpret_cast<uint4*>(out + (size_t)g * 64 + l * 8) = u;
}

// Layer 3 + mean-pool stage 1 fused: no global feature store.
// Same gather/transform; relu'd outputs staged in LDS (32 nodes x 64 ch),
// then per-channel run-length reduce over sorted batch -> few atomics/block.
__global__ __launch_bounds__(256) void agg_pool_kernel(const __half* __restrict__ prev,
                                                       const int2* __restrict__ csr,
                                                       const int* __restrict__ offs,
                                                       const float* __restrict__ W,
                                                       const float* __restrict__ bias,
                                                       const int* __restrict__ batch,
                                                       float* __restrict__ sums,
                                                       float* __restrict__ cnts, int N) {
    __shared__ float Wl[64 * 64];
    __shared__ float bl[64];
    __shared__ float nacc[32 * 64];
    __shared__ int grps[32];
    for (int i = threadIdx.x; i < 64 * 64; i += 256) Wl[i] = W[i];
    if (threadIdx.x < 64) bl[threadIdx.x] = bias[threadIdx.x];
    if (threadIdx.x < 32) {
        int gg = blockIdx.x * 32 + threadIdx.x;
        grps[threadIdx.x] = (gg < N) ? batch[gg] : -1;
    }
    __syncthreads();

    const int node = threadIdx.x >> 3;               // 0..31
    const int g = blockIdx.x * 32 + node;
    const int l = threadIdx.x & 7;
    const bool valid = g < N;

    float o[8] = {0.f, 0.f, 0.f, 0.f, 0.f, 0.f, 0.f, 0.f};
    if (valid) {
        int e0 = offs[g], e1 = offs[g + 1];
        float acc[8] = {0.f, 0.f, 0.f, 0.f, 0.f, 0.f, 0.f, 0.f};
        int e = e0;
        for (; e + 4 <= e1; e += 4) {
            int2 r0 = csr[e + 0];
            int2 r1 = csr[e + 1];
            int2 r2 = csr[e + 2];
            int2 r3 = csr[e + 3];
            GLOAD(r0, ua);
            GLOAD(r1, ub);
            GLOAD(r2, uc);
            GLOAD(r3, ud);
            GACC(ua, __int_as_float(r0.y));
            GACC(ub, __int_as_float(r1.y));
            GACC(uc, __int_as_float(r2.y));
            GACC(ud, __int_as_float(r3.y));
        }
        for (; e < e1; ++e) {
            int2 r = csr[e];
            GLOAD(r, ue);
            GACC(ue, __int_as_float(r.y));
        }
        #pragma unroll
        for (int j = 0; j < 8; ++j) o[j] = bl[l * 8 + j];
        #pragma unroll
        for (int k2 = 0; k2 < 8; ++k2) {
            float c[8];
            #pragma unroll
            for (int j = 0; j < 8; ++j) c[j] = __shfl(acc[j], k2, 8);
            #pragma unroll
            for (int j = 0; j < 8; ++j) {
                const float4 wa = *reinterpret_cast<const float4*>(Wl + (8 * k2 + j) * 64 + l * 8);
                const float4 wb = *reinterpret_cast<const float4*>(Wl + (8 * k2 + j) * 64 + l * 8 + 4);
                o[0] = fmaf(c[j], wa.x, o[0]); o[1] = fmaf(c[j], wa.y, o[1]);
                o[2] = fmaf(c[j], wa.z, o[2]); o[3] = fmaf(c[j], wa.w, o[3]);
                o[4] = fmaf(c[j], wb.x, o[4]); o[5] = fmaf(c[j], wb.y, o[5]);
                o[6] = fmaf(c[j], wb.z, o[6]); o[7] = fmaf(c[j], wb.w, o[7]);
            }
        }
    }
    #pragma unroll
    for (int j = 0; j < 8; ++j)
        nacc[node * 64 + l * 8 + j] = valid ? fmaxf(o[j], 0.f) : 0.f;
    __syncthreads();

    // run-length reduce: thread (ch, rq) sums its 8-node range per group run
    const int ch = threadIdx.x & 63;
    const int rq = threadIdx.x >> 6;     // 0..3, nodes rq*8..rq*8+7
    float racc = 0.f;
    int cur = -1;
    for (int j = rq * 8; j < rq * 8 + 8; ++j) {
        int gp = grps[j];
        if (gp != cur) {
            if (cur >= 0) atomicAdd(&sums[cur * 64 + ch], racc);
            cur = gp; racc = 0.f;
        }
        if (gp >= 0) racc += nacc[j * 64 + ch];
    }
    if (cur >= 0) atomicAdd(&sums[cur * 64 + ch], racc);
    if (ch == 0) {
        int cur2 = -1;
        float cc = 0.f;
        for (int j = rq * 8; j < rq * 8 + 8; ++j) {
            int gp = grps[j];
            if (gp != cur2) {
                if (cur2 >= 0) atomicAdd(&cnts[cur2], cc);
                cur2 = gp; cc = 0.f;
            }
            if (gp >= 0) cc += 1.f;
        }
        if (cur2 >= 0) atomicAdd(&cnts[cur2], cc);
    }
}

#undef GLOAD
#undef GACC

// MLP head: pooled[G][64] -> relu(@lw1 64x32) -> relu(@lw2 32x16) -> @lw3 16x1
__global__ __launch_bounds__(256) void head_kernel(const float* __restrict__ sums,
                                                   const float* __restrict__ cnts,
                                                   const float* __restrict__ lw1,
                                                   const float* __restrict__ lb1,
                                                   const float* __restrict__ lw2,
                                                   const float* __restrict__ lb2,
                                                   const float* __restrict__ lw3,
                                                   const float* __restrict__ lb3,
                                                   float* __restrict__ out, int G) {
    __shared__ float pooled[64 * 64];
    __shared__ float z1[64 * 32];
    __shared__ float z2[64 * 16];
    int tid = threadIdx.x;
    for (int i = tid; i < G * 64; i += 256) {
        int g = i >> 6;
        float cn = cnts[g];
        cn = (cn < 1.f) ? 1.f : cn;
        pooled[i] = sums[i] / cn;
    }
    __syncthreads();
    for (int i = tid; i < G * 32; i += 256) {
        int g = i >> 5, j = i & 31;
        float acc = lb1[j];
        #pragma unroll
        for (int k = 0; k < 64; ++k) acc = fmaf(pooled[g * 64 + k], lw1[k * 32 + j], acc);
        z1[i] = fmaxf(acc, 0.f);
    }
    __syncthreads();
    for (int i = tid; i < G * 16; i += 256) {
        int g = i >> 4, j = i & 15;
        float acc = lb2[j];
        #pragma unroll
        for (int k = 0; k < 32; ++k) acc = fmaf(z1[g * 32 + k], lw2[k * 16 + j], acc);
        z2[i] = fmaxf(acc, 0.f);
    }
    __syncthreads();
    if (tid < G) {
        float acc = lb3[0];
        #pragma unroll
        for (int k = 0; k < 16; ++k) acc = fmaf(z2[tid * 16 + k], lw3[k], acc);
        out[tid] = acc;
    }
}

static inline size_t align256(size_t x) { return (x + 255) & ~(size_t)255; }

extern "C" void kernel_launch(void* const* d_in, const int* in_sizes, int n_in,
                              void* d_out, int out_size, void* d_ws, size_t ws_size,
                              hipStream_t stream) {
    const float* x     = (const float*)d_in[0];
    const int*   ei    = (const int*)d_in[1];     // (2,E): [0..E)=src, [E..2E)=dst
    const float* ew    = (const float*)d_in[2];
    const int*   batch = (const int*)d_in[3];
    const float* W1 = (const float*)d_in[4];
    const float* b1 = (const float*)d_in[5];
    const float* W2 = (const float*)d_in[6];
    const float* b2 = (const float*)d_in[7];
    const float* W3 = (const float*)d_in[8];
    const float* b3 = (const float*)d_in[9];
    const float* lw1 = (const float*)d_in[10];
    const float* lb1 = (const float*)d_in[11];
    const float* lw2 = (const float*)d_in[12];
    const float* lb2 = (const float*)d_in[13];
    const float* lw3 = (const float*)d_in[14];
    const float* lb3 = (const float*)d_in[15];
    float* out = (float*)d_out;

    const int N = in_sizes[0] / 64;
    const int E = in_sizes[2];
    const int G = out_size;
    const int K = (N + 255) >> 8;
    const int chunk = (E + KNBLK - 1) / KNBLK;

    // Workspace carve. ebuf (int2, 6.4MB) aliases xh (6.4MB; dead before conv).
    char* w = (char*)d_ws;
    size_t off = 0;
    auto carve = [&](size_t bytes) -> void* {
        void* p = w + off;
        off = align256(off + bytes);
        return p;
    };
    __half* xh    = (__half*)carve((size_t)N * 64 * 2);
    __half* hA    = (__half*)carve((size_t)N * 64 * 2);
    __half* hB    = (__half*)carve((size_t)N * 64 * 2);
    int2*  csr    = (int2*)carve((size_t)E * 8);
    int*   counts = (int*)carve((size_t)KNBLK * K * 4);
    int*   btot   = (int*)carve((size_t)K * 4);
    int*   bb0    = (int*)carve((size_t)(K + 1) * 4);
    int*   offs   = (int*)carve((size_t)(N + 1) * 4);
    float* sums   = (float*)carve((size_t)G * 64 * 4);
    float* cnts   = (float*)carve((size_t)G * 4);
    int2*  ebuf   = (int2*)xh;     // 800K*8B = 6.4MB fits in xh; dead after passC
    (void)ws_size; (void)n_in;

    // ---- CSR build: bucketed counting sort (dense writes throughout) ----
    histA_kernel <<<KNBLK, 256, 0, stream>>>(ei, counts, E, K, chunk);
    scanB1_kernel<<<K,     256, 0, stream>>>(counts, btot, K);
    scanB2_kernel<<<1,     256, 0, stream>>>(btot, bb0, K, sums, cnts, G);
    passB_kernel <<<KNBLK, 256, 0, stream>>>(ei, ew, counts, bb0, ebuf, E, K, chunk);
    passC_kernel <<<K,     256, 0, stream>>>(ebuf, bb0, csr, offs, N, E, K);

    // ---- x -> fp16 (after passC: xh aliases ebuf) ----
    const int n4 = N * 64 / 4;
    conv_kernel<<<(n4 + 255) / 256, 256, 0, stream>>>(x, xh, n4);

    const int AGG_BLOCKS = (int)(((size_t)N * 8 + 255) / 256);

    // ---- layers 1-2 store fp16; layer 3 fused with pool ----
    agg_fused_kernel<<<AGG_BLOCKS, 256, 0, stream>>>(xh, csr, offs, W1, b1, hA, N);
    agg_fused_kernel<<<AGG_BLOCKS, 256, 0, stream>>>(hA, csr, offs, W2, b2, hB, N);
    agg_pool_kernel <<<AGG_BLOCKS, 256, 0, stream>>>(hB, csr, offs, W3, b3,
                                                     batch, sums, cnts, N);

    // ---- head ----
    head_kernel<<<1, 256, 0, stream>>>(sums, cnts, lw1, lb1, lw2, lb2, lw3, lb3, out, G);
}

// Round 17
// 157.841 us; speedup vs baseline: 1.1040x; 1.1040x over previous
//
#include <hip/hip_runtime.h>
#include <hip/hip_bf16.h>
#include <hip/hip_fp16.h>

// GCN regressor: 3x GCNConv(64->64, normalize=False) + mean-pool + MLP(64->32->16->1)
// Round 17: REVERT round-16 agg_pool fusion (74us vs 25+10: LDS occupancy + block-
// wide sync + bank conflicts). Back to round-14 best structure (165.9us):
//  - 3x agg_fused (8 lanes/node, x4 unroll, fp16 table) + separate pool.
//  - scanB2 keeps sums/cnts zero-init fold.
//  NEW: conv fused into histA (independent work, one dispatch fewer);
//       ebuf un-aliased from xh to allow it.

#define HID 64
#define KNBLK 256

// ---- pass A: per-block per-bucket histogram (bucket = dst>>8) + x->fp16 conv ----
__global__ __launch_bounds__(256) void histA_conv_kernel(const int* __restrict__ ei,
                                                         int* __restrict__ counts,
                                                         const float* __restrict__ x,
                                                         __half* __restrict__ xh,
                                                         int E, int K, int chunk, int n4) {
    __shared__ int hist[256];
    int t = threadIdx.x, b = blockIdx.x;
    hist[t] = 0;
    __syncthreads();
    int s = b * chunk, e1 = min(E, s + chunk);
    for (int i = s + t; i < e1; i += 256)
        atomicAdd(&hist[ei[E + i] >> 8], 1);
    // conv interleaved (independent): grid-stride over n4 float4 groups
    for (int i = b * 256 + t; i < n4; i += 256 * KNBLK) {
        const float4 v = *reinterpret_cast<const float4*>(x + (size_t)i * 4);
        __half2 a = __float22half2_rn(make_float2(v.x, v.y));
        __half2 b2 = __float22half2_rn(make_float2(v.z, v.w));
        uint2 u;
        u.x = __builtin_bit_cast(unsigned int, a);
        u.y = __builtin_bit_cast(unsigned int, b2);
        *reinterpret_cast<uint2*>(xh + (size_t)i * 4) = u;
    }
    __syncthreads();
    if (t < K) counts[b * K + t] = hist[t];
}

// ---- scan B1 ----
__global__ __launch_bounds__(256) void scanB1_kernel(int* __restrict__ counts,
                                                     int* __restrict__ btot, int K) {
    __shared__ int sh[256];
    int k = blockIdx.x, t = threadIdx.x;
    int v = counts[t * K + k];
    sh[t] = v;
    __syncthreads();
    #pragma unroll
    for (int d = 1; d < 256; d <<= 1) {
        int add = (t >= d) ? sh[t - d] : 0;
        __syncthreads();
        sh[t] += add;
        __syncthreads();
    }
    counts[t * K + k] = sh[t] - v;
    if (t == 255) btot[k] = sh[255];
}

// ---- scan B2 (+ zero-init of pool accumulators) ----
__global__ __launch_bounds__(256) void scanB2_kernel(const int* __restrict__ btot,
                                                     int* __restrict__ bb0, int K,
                                                     float* __restrict__ sums,
                                                     float* __restrict__ cnts, int G) {
    __shared__ int sh[256];
    int t = threadIdx.x;
    int v = (t < K) ? btot[t] : 0;
    sh[t] = v;
    __syncthreads();
    #pragma unroll
    for (int d = 1; d < 256; d <<= 1) {
        int add = (t >= d) ? sh[t - d] : 0;
        __syncthreads();
        sh[t] += add;
        __syncthreads();
    }
    if (t < K) bb0[t] = sh[t] - v;
    if (t == 255) bb0[K] = sh[255];
    for (int i = t; i < G * 64; i += 256) sums[i] = 0.f;
    if (t < G) cnts[t] = 0.f;
}

// ---- pass B: scatter edges to bucket-partitioned ebuf (packed int2 records) ----
__global__ __launch_bounds__(256) void passB_kernel(const int* __restrict__ ei,
                                                    const float* __restrict__ ew,
                                                    const int* __restrict__ counts,
                                                    const int* __restrict__ bb0,
                                                    int2* __restrict__ ebuf,
                                                    int E, int K, int chunk) {
    __shared__ int lcur[256];
    int t = threadIdx.x, b = blockIdx.x;
    lcur[t] = 0;
    __syncthreads();
    int s = b * chunk, e1 = min(E, s + chunk);
    for (int i = s + t; i < e1; i += 256) {
        int src = ei[i];
        int dst = ei[E + i];
        float w = ew[i];
        int k = dst >> 8;
        int idx = atomicAdd(&lcur[k], 1);
        int slot = bb0[k] + counts[b * K + k] + idx;
        ebuf[slot] = make_int2(src | ((dst & 255) << 16), __float_as_int(w));
    }
}

// ---- pass C: per-bucket counting sort -> final CSR (int2{src,wbits}) + offs ----
__global__ __launch_bounds__(256) void passC_kernel(const int2* __restrict__ ebuf,
                                                    const int* __restrict__ bb0,
                                                    int2* __restrict__ csr,
                                                    int* __restrict__ offs,
                                                    int N, int E, int K) {
    __shared__ int ldeg[256];
    __shared__ int sh[256];
    __shared__ int lofs[256];
    int b = blockIdx.x, t = threadIdx.x;
    int gb0 = bb0[b], gb1 = bb0[b + 1];
    int cnt = gb1 - gb0;
    int base = b << 8;
    ldeg[t] = 0;
    __syncthreads();
    for (int i = t; i < cnt; i += 256)
        atomicAdd(&ldeg[(ebuf[gb0 + i].x >> 16) & 255], 1);
    __syncthreads();
    int v = ldeg[t];
    sh[t] = v;
    __syncthreads();
    #pragma unroll
    for (int d = 1; d < 256; d <<= 1) {
        int add = (t >= d) ? sh[t - d] : 0;
        __syncthreads();
        sh[t] += add;
        __syncthreads();
    }
    lofs[t] = sh[t] - v;
    int nInB = min(256, N - base);
    if (t < nInB) offs[base + t] = gb0 + lofs[t];
    if (b == K - 1 && t == 0) offs[N] = E;
    __syncthreads();
    for (int i = t; i < cnt; i += 256) {
        int2 r = ebuf[gb0 + i];
        int d = (r.x >> 16) & 255;
        int pos = atomicAdd(&lofs[d], 1);
        csr[gb0 + pos] = make_int2(r.x & 0xFFFF, r.y);
    }
}

// Fused layer: out[n][:] = relu( (sum_{e in CSR(n)} w_e * prev[src_e][:]) @ W + b )
// 8 lanes/node; lane l owns channels 8l..8l+7 (one uint4 = 16B fp16 load).
// fp32 accumulate; x4 unroll; width-8 shfl epilogue; 16B fp16 store.
__global__ __launch_bounds__(256) void agg_fused_kernel(const __half* __restrict__ prev,
                                                        const int2* __restrict__ csr,
                                                        const int* __restrict__ offs,
                                                        const float* __restrict__ W,
                                                        const float* __restrict__ bias,
                                                        __half* __restrict__ out, int N) {
    __shared__ float Wl[64 * 64];
    __shared__ float bl[64];
    for (int i = threadIdx.x; i < 64 * 64; i += 256) Wl[i] = W[i];
    if (threadIdx.x < 64) bl[threadIdx.x] = bias[threadIdx.x];
    __syncthreads();

    int g = (blockIdx.x * 256 + threadIdx.x) >> 3;   // node (8 lanes each)
    int l = threadIdx.x & 7;                         // lane: channels 8l..8l+7
    if (g >= N) return;

    int e0 = offs[g], e1 = offs[g + 1];
    float acc[8] = {0.f, 0.f, 0.f, 0.f, 0.f, 0.f, 0.f, 0.f};

    #define GLOAD(R, U)                                                              \
        const uint4 U = *reinterpret_cast<const uint4*>(prev + (size_t)(R).x * 64 + l * 8);
    #define GACC(U, WW)                                                              \
        {                                                                            \
            const float2 f0 = __half22float2(__builtin_bit_cast(__half2, (U).x));    \
            const float2 f1 = __half22float2(__builtin_bit_cast(__half2, (U).y));    \
            const float2 f2 = __half22float2(__builtin_bit_cast(__half2, (U).z));    \
            const float2 f3 = __half22float2(__builtin_bit_cast(__half2, (U).w));    \
            acc[0] = fmaf((WW), f0.x, acc[0]); acc[1] = fmaf((WW), f0.y, acc[1]);    \
            acc[2] = fmaf((WW), f1.x, acc[2]); acc[3] = fmaf((WW), f1.y, acc[3]);    \
            acc[4] = fmaf((WW), f2.x, acc[4]); acc[5] = fmaf((WW), f2.y, acc[5]);    \
            acc[6] = fmaf((WW), f3.x, acc[6]); acc[7] = fmaf((WW), f3.y, acc[7]);    \
        }

    int e = e0;
    for (; e + 4 <= e1; e += 4) {
        int2 r0 = csr[e + 0];
        int2 r1 = csr[e + 1];
        int2 r2 = csr[e + 2];
        int2 r3 = csr[e + 3];
        GLOAD(r0, ua);
        GLOAD(r1, ub);
        GLOAD(r2, uc);
        GLOAD(r3, ud);
        GACC(ua, __int_as_float(r0.y));
        GACC(ub, __int_as_float(r1.y));
        GACC(uc, __int_as_float(r2.y));
        GACC(ud, __int_as_float(r3.y));
    }
    for (; e < e1; ++e) {
        int2 r = csr[e];
        GLOAD(r, ue);
        GACC(ue, __int_as_float(r.y));
    }
    #undef GLOAD
    #undef GACC

    float o[8];
    #pragma unroll
    for (int j = 0; j < 8; ++j) o[j] = bl[l * 8 + j];
    #pragma unroll
    for (int k2 = 0; k2 < 8; ++k2) {
        float c[8];
        #pragma unroll
        for (int j = 0; j < 8; ++j) c[j] = __shfl(acc[j], k2, 8);
        #pragma unroll
        for (int j = 0; j < 8; ++j) {
            const float4 wa = *reinterpret_cast<const float4*>(Wl + (8 * k2 + j) * 64 + l * 8);
            const float4 wb = *reinterpret_cast<const float4*>(Wl + (8 * k2 + j) * 64 + l * 8 + 4);
            o[0] = fmaf(c[j], wa.x, o[0]); o[1] = fmaf(c[j], wa.y, o[1]);
            o[2] = fmaf(c[j], wa.z, o[2]); o[3] = fmaf(c[j], wa.w, o[3]);
            o[4] = fmaf(c[j], wb.x, o[4]); o[5] = fmaf(c[j], wb.y, o[5]);
            o[6] = fmaf(c[j], wb.z, o[6]); o[7] = fmaf(c[j], wb.w, o[7]);
        }
    }
    uint4 u;
    u.x = __builtin_bit_cast(unsigned int,
          __float22half2_rn(make_float2(fmaxf(o[0], 0.f), fmaxf(o[1], 0.f))));
    u.y = __builtin_bit_cast(unsigned int,
          __float22half2_rn(make_float2(fmaxf(o[2], 0.f), fmaxf(o[3], 0.f))));
    u.z = __builtin_bit_cast(unsigned int,
          __float22half2_rn(make_float2(fmaxf(o[4], 0.f), fmaxf(o[5], 0.f))));
    u.w = __builtin_bit_cast(unsigned int,
          __float22half2_rn(make_float2(fmaxf(o[6], 0.f), fmaxf(o[7], 0.f))));
    *reinterpret_cast<uint4*>(out + (size_t)g * 64 + l * 8) = u;
}

// Mean-pool stage 1 (fp16 input): sorted batch -> register run-length accumulate.
__global__ __launch_bounds__(256) void pool_kernel(const __half* __restrict__ a,
                                                   const int* __restrict__ batch,
                                                   float* __restrict__ sums,
                                                   float* __restrict__ cnts, int N) {
    int c = threadIdx.x & 63;
    int sub = threadIdx.x >> 6;   // 0..3
    int chunk = (N + gridDim.x - 1) / gridDim.x;
    int start = blockIdx.x * chunk;
    int end = min(N, start + chunk);
    int curg = -1;
    float acc = 0.f, cacc = 0.f;
    for (int n = start + sub; n < end; n += 4) {
        int g = batch[n];
        if (g != curg) {
            if (curg >= 0) {
                atomicAdd(&sums[curg * 64 + c], acc);
                if (c == 0) atomicAdd(&cnts[curg], cacc);
            }
            curg = g; acc = 0.f; cacc = 0.f;
        }
        acc += __half2float(a[(size_t)n * 64 + c]);
        cacc += 1.f;
    }
    if (curg >= 0) {
        atomicAdd(&sums[curg * 64 + c], acc);
        if (c == 0) atomicAdd(&cnts[curg], cacc);
    }
}

// MLP head: pooled[G][64] -> relu(@lw1 64x32) -> relu(@lw2 32x16) -> @lw3 16x1
__global__ __launch_bounds__(256) void head_kernel(const float* __restrict__ sums,
                                                   const float* __restrict__ cnts,
                                                   const float* __restrict__ lw1,
                                                   const float* __restrict__ lb1,
                                                   const float* __restrict__ lw2,
                                                   const float* __restrict__ lb2,
                                                   const float* __restrict__ lw3,
                                                   const float* __restrict__ lb3,
                                                   float* __restrict__ out, int G) {
    __shared__ float pooled[64 * 64];
    __shared__ float z1[64 * 32];
    __shared__ float z2[64 * 16];
    int tid = threadIdx.x;
    for (int i = tid; i < G * 64; i += 256) {
        int g = i >> 6;
        float cn = cnts[g];
        cn = (cn < 1.f) ? 1.f : cn;
        pooled[i] = sums[i] / cn;
    }
    __syncthreads();
    for (int i = tid; i < G * 32; i += 256) {
        int g = i >> 5, j = i & 31;
        float acc = lb1[j];
        #pragma unroll
        for (int k = 0; k < 64; ++k) acc = fmaf(pooled[g * 64 + k], lw1[k * 32 + j], acc);
        z1[i] = fmaxf(acc, 0.f);
    }
    __syncthreads();
    for (int i = tid; i < G * 16; i += 256) {
        int g = i >> 4, j = i & 15;
        float acc = lb2[j];
        #pragma unroll
        for (int k = 0; k < 32; ++k) acc = fmaf(z1[g * 32 + k], lw2[k * 16 + j], acc);
        z2[i] = fmaxf(acc, 0.f);
    }
    __syncthreads();
    if (tid < G) {
        float acc = lb3[0];
        #pragma unroll
        for (int k = 0; k < 16; ++k) acc = fmaf(z2[tid * 16 + k], lw3[k], acc);
        out[tid] = acc;
    }
}

static inline size_t align256(size_t x) { return (x + 255) & ~(size_t)255; }

extern "C" void kernel_launch(void* const* d_in, const int* in_sizes, int n_in,
                              void* d_out, int out_size, void* d_ws, size_t ws_size,
                              hipStream_t stream) {
    const float* x     = (const float*)d_in[0];
    const int*   ei    = (const int*)d_in[1];     // (2,E): [0..E)=src, [E..2E)=dst
    const float* ew    = (const float*)d_in[2];
    const int*   batch = (const int*)d_in[3];
    const float* W1 = (const float*)d_in[4];
    const float* b1 = (const float*)d_in[5];
    const float* W2 = (const float*)d_in[6];
    const float* b2 = (const float*)d_in[7];
    const float* W3 = (const float*)d_in[8];
    const float* b3 = (const float*)d_in[9];
    const float* lw1 = (const float*)d_in[10];
    const float* lb1 = (const float*)d_in[11];
    const float* lw2 = (const float*)d_in[12];
    const float* lb2 = (const float*)d_in[13];
    const float* lw3 = (const float*)d_in[14];
    const float* lb3 = (const float*)d_in[15];
    float* out = (float*)d_out;

    const int N = in_sizes[0] / 64;
    const int E = in_sizes[2];
    const int G = out_size;
    const int K = (N + 255) >> 8;
    const int chunk = (E + KNBLK - 1) / KNBLK;

    // Workspace carve. ebuf now separate (conv fused into histA writes xh early).
    char* w = (char*)d_ws;
    size_t off = 0;
    auto carve = [&](size_t bytes) -> void* {
        void* p = w + off;
        off = align256(off + bytes);
        return p;
    };
    __half* xh    = (__half*)carve((size_t)N * 64 * 2);
    __half* hA    = (__half*)carve((size_t)N * 64 * 2);
    __half* hB    = (__half*)carve((size_t)N * 64 * 2);
    int2*  csr    = (int2*)carve((size_t)E * 8);
    int2*  ebuf   = (int2*)carve((size_t)E * 8);
    int*   counts = (int*)carve((size_t)KNBLK * K * 4);
    int*   btot   = (int*)carve((size_t)K * 4);
    int*   bb0    = (int*)carve((size_t)(K + 1) * 4);
    int*   offs   = (int*)carve((size_t)(N + 1) * 4);
    float* sums   = (float*)carve((size_t)G * 64 * 4);
    float* cnts   = (float*)carve((size_t)G * 4);
    (void)ws_size; (void)n_in;

    const int n4 = N * 64 / 4;

    // ---- CSR build (hist fused with x->fp16 conv) ----
    histA_conv_kernel<<<KNBLK, 256, 0, stream>>>(ei, counts, x, xh, E, K, chunk, n4);
    scanB1_kernel<<<K,     256, 0, stream>>>(counts, btot, K);
    scanB2_kernel<<<1,     256, 0, stream>>>(btot, bb0, K, sums, cnts, G);
    passB_kernel <<<KNBLK, 256, 0, stream>>>(ei, ew, counts, bb0, ebuf, E, K, chunk);
    passC_kernel <<<K,     256, 0, stream>>>(ebuf, bb0, csr, offs, N, E, K);

    const int AGG_BLOCKS = (int)(((size_t)N * 8 + 255) / 256);

    // ---- 3 fused layers: agg (fp16 gather, fp32 accum) -> @W + b -> relu ----
    agg_fused_kernel<<<AGG_BLOCKS, 256, 0, stream>>>(xh, csr, offs, W1, b1, hA, N);
    agg_fused_kernel<<<AGG_BLOCKS, 256, 0, stream>>>(hA, csr, offs, W2, b2, hB, N);
    agg_fused_kernel<<<AGG_BLOCKS, 256, 0, stream>>>(hB, csr, offs, W3, b3, hA, N);

    // ---- pool + head ----
    pool_kernel<<<1024, 256, 0, stream>>>(hA, batch, sums, cnts, N);
    head_kernel<<<1, 256, 0, stream>>>(sums, cnts, lw1, lb1, lw2, lb2, lw3, lb3, out, G);
}